// Round 2
// baseline (283.654 us; speedup 1.0000x reference)
//
#include <hip/hip_runtime.h>

namespace {

constexpr int F_FEAT = 310;
constexpr int KDIM   = 309;   // F_FEAT - 1
constexpr int BSZ    = 2048;
constexpr int HDIM   = 32;
constexpr int BBLK   = 256;   // samples per workgroup
constexpr int CJ     = 16;    // K-chunk for layer 1

__global__ __launch_bounds__(256) void sfp_fused(
    const float* __restrict__ x,
    const float* __restrict__ W1, const float* __restrict__ b1,
    const float* __restrict__ W2, const float* __restrict__ b2,
    const float* __restrict__ W3, const float* __restrict__ b3,
    float* __restrict__ out)
{
    __shared__ float A_lds[CJ][BBLK + 4];   // [j][b]; +4 pad -> <=2-way banks (free)
    __shared__ float W1s[CJ][HDIM];
    __shared__ float h_lds[BBLK][HDIM + 1]; // [b][h]; +1 pad -> <=2-way banks
    __shared__ float W2s[HDIM][HDIM];
    __shared__ float W3s[HDIM][HDIM];
    __shared__ float b1s[HDIM], b2s[HDIM], b3s[HDIM];

    const int tid = threadIdx.x;
    const int bid = blockIdx.x;
    const int fi  = bid >> 3;          // feature index 0..309
    const int b0  = (bid & 7) << 8;    // sample base (0..1792)
    const int hg  = tid & 7;           // h = hg*4 + c
    const int sg  = tid >> 3;          // b_local = sg*8 + t
    const int iB  = fi << 11;          // fi * 2048: flat-index skip threshold

    const float* __restrict__ W1g = W1 + (size_t)fi * (KDIM * HDIM);

    { // stage layer-2/3 weights + biases once
        const float* W2g = W2 + (size_t)fi * (HDIM * HDIM);
        const float* W3g = W3 + (size_t)fi * (HDIM * HDIM);
        for (int t = tid; t < HDIM * HDIM; t += 256) {
            W2s[t >> 5][t & 31] = W2g[t];
            W3s[t >> 5][t & 31] = W3g[t];
        }
        if (tid < HDIM) {
            b1s[tid] = b1[fi * HDIM + tid];
            b2s[tid] = b2[fi * HDIM + tid];
            b3s[tid] = b3[fi * HDIM + tid];
        }
    }

    float acc[8][4];
    #pragma unroll
    for (int t = 0; t < 8; ++t)
        #pragma unroll
        for (int c = 0; c < 4; ++c) acc[t][c] = 0.f;

    const int jl_s = tid & 15;   // staging: j-lane
    const int br_s = tid >> 4;   // staging: base row (0..15)

    // ---------------- layer 1: (256 x 309) @ (309 x 32) ----------------
    for (int j0 = 0; j0 < KDIM; j0 += CJ) {
        const int cj = (KDIM - j0) < CJ ? (KDIM - j0) : CJ;
        __syncthreads();   // previous chunk's reads complete before overwrite
        if (jl_s < cj) {
            #pragma unroll
            for (int p = 0; p < BBLK / 16; ++p) {
                const int b   = br_s + p * 16;
                const int lin = (b0 + b) * KDIM + j0 + jl_s;    // LOO flat index
                const int gix = lin + ((lin >= iB) ? BSZ : 0);  // skip deleted row
                A_lds[jl_s][b] = x[gix];
            }
        }
        for (int t = tid; t < cj * HDIM; t += 256)
            W1s[t >> 5][t & 31] = W1g[j0 * HDIM + t];
        __syncthreads();

        for (int jl = 0; jl < cj; ++jl) {
            const float4 wv = *(const float4*)&W1s[jl][hg * 4];
            const float4 a0 = *(const float4*)&A_lds[jl][sg * 8];
            const float4 a1 = *(const float4*)&A_lds[jl][sg * 8 + 4];
            const float av[8] = {a0.x, a0.y, a0.z, a0.w, a1.x, a1.y, a1.z, a1.w};
            const float wc[4] = {wv.x, wv.y, wv.z, wv.w};
            #pragma unroll
            for (int t = 0; t < 8; ++t)
                #pragma unroll
                for (int c = 0; c < 4; ++c)
                    acc[t][c] = fmaf(av[t], wc[c], acc[t][c]);
        }
    }

    // bias + relu -> h_lds
    #pragma unroll
    for (int t = 0; t < 8; ++t)
        #pragma unroll
        for (int c = 0; c < 4; ++c) {
            const float v = acc[t][c] + b1s[hg * 4 + c];
            h_lds[sg * 8 + t][hg * 4 + c] = v > 0.f ? v : 0.f;
        }
    __syncthreads();

    // ---------------- layer 2: (256 x 32) @ (32 x 32) ----------------
    float acc2[8][4];
    #pragma unroll
    for (int t = 0; t < 8; ++t)
        #pragma unroll
        for (int c = 0; c < 4; ++c) acc2[t][c] = 0.f;

    for (int k = 0; k < HDIM; ++k) {
        const float4 wv = *(const float4*)&W2s[k][hg * 4];
        const float wc[4] = {wv.x, wv.y, wv.z, wv.w};
        float a[8];
        #pragma unroll
        for (int t = 0; t < 8; ++t) a[t] = h_lds[sg * 8 + t][k];
        #pragma unroll
        for (int t = 0; t < 8; ++t)
            #pragma unroll
            for (int c = 0; c < 4; ++c)
                acc2[t][c] = fmaf(a[t], wc[c], acc2[t][c]);
    }
    __syncthreads();   // all h1 reads done before overwrite
    #pragma unroll
    for (int t = 0; t < 8; ++t)
        #pragma unroll
        for (int c = 0; c < 4; ++c) {
            const float v = acc2[t][c] + b2s[hg * 4 + c];
            h_lds[sg * 8 + t][hg * 4 + c] = v > 0.f ? v : 0.f;
        }
    __syncthreads();

    // ---------------- layer 3: (256 x 32) @ (32 x 32) ----------------
    float acc3[8][4];
    #pragma unroll
    for (int t = 0; t < 8; ++t)
        #pragma unroll
        for (int c = 0; c < 4; ++c) acc3[t][c] = 0.f;

    for (int k = 0; k < HDIM; ++k) {
        const float4 wv = *(const float4*)&W3s[k][hg * 4];
        const float wc[4] = {wv.x, wv.y, wv.z, wv.w};
        float a[8];
        #pragma unroll
        for (int t = 0; t < 8; ++t) a[t] = h_lds[sg * 8 + t][k];
        #pragma unroll
        for (int t = 0; t < 8; ++t)
            #pragma unroll
            for (int c = 0; c < 4; ++c)
                acc3[t][c] = fmaf(a[t], wc[c], acc3[t][c]);
    }

    // ---------------- epilogue: bias + relu + fp32 store ----------------
    const size_t obase = ((size_t)fi * BSZ + b0) * HDIM;
    #pragma unroll
    for (int t = 0; t < 8; ++t) {
        float4 v;
        float r;
        r = acc3[t][0] + b3s[hg * 4 + 0]; v.x = r > 0.f ? r : 0.f;
        r = acc3[t][1] + b3s[hg * 4 + 1]; v.y = r > 0.f ? r : 0.f;
        r = acc3[t][2] + b3s[hg * 4 + 2]; v.z = r > 0.f ? r : 0.f;
        r = acc3[t][3] + b3s[hg * 4 + 3]; v.w = r > 0.f ? r : 0.f;
        *(float4*)&out[obase + (size_t)(sg * 8 + t) * HDIM + hg * 4] = v;
    }
}

} // namespace

extern "C" void kernel_launch(void* const* d_in, const int* in_sizes, int n_in,
                              void* d_out, int out_size, void* d_ws, size_t ws_size,
                              hipStream_t stream) {
    const float* x  = (const float*)d_in[0];
    const float* W1 = (const float*)d_in[1];
    const float* b1 = (const float*)d_in[2];
    const float* W2 = (const float*)d_in[3];
    const float* b2 = (const float*)d_in[4];
    const float* W3 = (const float*)d_in[5];
    const float* b3 = (const float*)d_in[6];
    float* out = (float*)d_out;

    const dim3 grid(F_FEAT * (BSZ / BBLK));  // 310 * 8 = 2480
    const dim3 block(256);
    hipLaunchKernelGGL(sfp_fused, grid, block, 0, stream,
                       x, W1, b1, W2, b2, W3, b3, out);
}

// Round 3
// 108.803 us; speedup vs baseline: 2.6071x; 2.6071x over previous
//
#include <hip/hip_runtime.h>

namespace {

constexpr int F_FEAT = 310;
constexpr int KDIM   = 309;   // F_FEAT - 1
constexpr int BSZ    = 2048;
constexpr int HDIM   = 32;
constexpr int BBLK   = 128;   // samples per workgroup
constexpr int NCH    = 10;    // K-chunks of 32 (309 -> 320 zero-padded)
constexpr int LDA    = 40;    // LDS row stride (elements); 80 B -> conflict-free b128

typedef __bf16 bf16x8 __attribute__((ext_vector_type(8)));
typedef __bf16 bf16x4 __attribute__((ext_vector_type(4)));
typedef float  f32x4  __attribute__((ext_vector_type(4)));

#define MFMA(a, b, c) __builtin_amdgcn_mfma_f32_16x16x32_bf16((a), (b), (c), 0, 0, 0)

__global__ __launch_bounds__(256, 4) void sfp_mfma(
    const float* __restrict__ x,
    const float* __restrict__ W1, const float* __restrict__ b1,
    const float* __restrict__ W2, const float* __restrict__ b2,
    const float* __restrict__ W3, const float* __restrict__ b3,
    float* __restrict__ out)
{
    __shared__ __attribute__((aligned(16))) __bf16 Abuf[2][BBLK * LDA]; // 2 x 10240 B
    __shared__ __attribute__((aligned(16))) __bf16 W1T[2][HDIM * LDA];  // 2 x 2560 B
    __shared__ __attribute__((aligned(16))) __bf16 h1s[BBLK * LDA];     // 10240 B
    __shared__ __attribute__((aligned(16))) __bf16 W2T[HDIM * LDA];     // 2560 B
    __shared__ __attribute__((aligned(16))) __bf16 W3T[HDIM * LDA];     // 2560 B
    // total 40960 B -> 3-4 WG/CU

    const int tid  = threadIdx.x;
    const int lane = tid & 63;
    const int wv   = tid >> 6;          // wave 0..3 -> samples wv*32..wv*32+31
    const int l15  = lane & 15;
    const int lk8  = (lane >> 4) * 8;   // fragment k-offset
    const int r0   = (lane >> 4) * 4;   // C/D row offset within 16x16 tile
    const int bid  = blockIdx.x;
    const int fi   = bid >> 4;          // feature 0..309
    const int b0   = (bid & 15) << 7;   // sample base
    const int iB   = fi << 11;          // LOO skip threshold (flat index)

    const float* __restrict__ W1g = W1 + (size_t)fi * (KDIM * HDIM);

    // biases: 2 columns per lane per layer (L1/L2-cached scalar loads)
    const float b1v0 = b1[fi*HDIM + l15], b1v1 = b1[fi*HDIM + 16 + l15];
    const float b2v0 = b2[fi*HDIM + l15], b2v1 = b2[fi*HDIM + 16 + l15];
    const float b3v0 = b3[fi*HDIM + l15], b3v1 = b3[fi*HDIM + 16 + l15];

    // ---- stage W2^T / W3^T once ----
    {
        const int kl = tid >> 3;          // k-row 0..31
        const int h0 = (tid & 7) * 4;     // h quad
        const float4 f2 = *(const float4*)&W2[(size_t)fi*HDIM*HDIM + kl*HDIM + h0];
        const float4 f3 = *(const float4*)&W3[(size_t)fi*HDIM*HDIM + kl*HDIM + h0];
        W2T[(h0+0)*LDA + kl] = (__bf16)f2.x; W2T[(h0+1)*LDA + kl] = (__bf16)f2.y;
        W2T[(h0+2)*LDA + kl] = (__bf16)f2.z; W2T[(h0+3)*LDA + kl] = (__bf16)f2.w;
        W3T[(h0+0)*LDA + kl] = (__bf16)f3.x; W3T[(h0+1)*LDA + kl] = (__bf16)f3.y;
        W3T[(h0+2)*LDA + kl] = (__bf16)f3.z; W3T[(h0+3)*LDA + kl] = (__bf16)f3.w;
    }

    const int kq4 = (tid & 7) * 4;   // k within chunk (0..28), 8 threads/sample
    const int sb  = tid >> 3;        // sample 0..31 (4 passes of 32)
    const int klw = tid >> 3;        // W1 staging k-row
    const int h0w = (tid & 7) * 4;

    // ---- prologue: stage chunk 0 into buffer 0 ----
    {
        #pragma unroll
        for (int p = 0; p < 4; ++p) {
            const int s   = sb + 32*p;
            const int lin = (b0 + s)*KDIM + kq4;   // chunk 0 always fully in-range k
            const bool hi = (lin >= iB);
            float4 f;
            if (hi || (lin + 3 < iB)) {
                f = *(const float4*)&x[lin + (hi ? BSZ : 0)];
            } else {
                float e[4];
                #pragma unroll
                for (int q = 0; q < 4; ++q) { const int l2 = lin + q; e[q] = x[l2 + (l2 >= iB ? BSZ : 0)]; }
                f = make_float4(e[0], e[1], e[2], e[3]);
            }
            bf16x4 v = {(__bf16)f.x, (__bf16)f.y, (__bf16)f.z, (__bf16)f.w};
            *(bf16x4*)&Abuf[0][s*LDA + kq4] = v;
        }
        const float4 fw = *(const float4*)&W1g[klw*HDIM + h0w];
        W1T[0][(h0w+0)*LDA + klw] = (__bf16)fw.x;
        W1T[0][(h0w+1)*LDA + klw] = (__bf16)fw.y;
        W1T[0][(h0w+2)*LDA + klw] = (__bf16)fw.z;
        W1T[0][(h0w+3)*LDA + klw] = (__bf16)fw.w;
    }
    __syncthreads();

    // ---- layer 1 K-loop: double-buffered, issue-early / write-late ----
    f32x4 acc00 = {0.f,0.f,0.f,0.f}, acc01 = {0.f,0.f,0.f,0.f};
    f32x4 acc10 = {0.f,0.f,0.f,0.f}, acc11 = {0.f,0.f,0.f,0.f};

    for (int c = 0; c < NCH; ++c) {
        const bool more = (c + 1 < NCH);
        float4 fa[4];
        float4 fw = make_float4(0.f, 0.f, 0.f, 0.f);
        if (more) {   // issue next-chunk global loads (HBM/L2 latency hides under MFMA)
            const int j0 = (c + 1) * 32;
            const int k0 = j0 + kq4;
            const bool fullk = (k0 + 3 < KDIM);
            #pragma unroll
            for (int p = 0; p < 4; ++p) {
                const int s   = sb + 32*p;
                const int lin = (b0 + s)*KDIM + k0;
                const bool hi = (lin >= iB);
                if (fullk && (hi || (lin + 3 < iB))) {
                    fa[p] = *(const float4*)&x[lin + (hi ? BSZ : 0)];
                } else {
                    float e[4];
                    #pragma unroll
                    for (int q = 0; q < 4; ++q) {
                        const int kk = k0 + q, l2 = lin + q;
                        e[q] = (kk < KDIM) ? x[l2 + (l2 >= iB ? BSZ : 0)] : 0.f;
                    }
                    fa[p] = make_float4(e[0], e[1], e[2], e[3]);
                }
            }
            const int kk = j0 + klw;
            if (kk < KDIM) fw = *(const float4*)&W1g[kk*HDIM + h0w];
        }
        // compute current chunk
        {
            const __bf16* Ab = Abuf[c & 1];
            const __bf16* Wb = W1T[c & 1];
            bf16x8 a0 = *(const bf16x8*)&Ab[(wv*32 +      l15)*LDA + lk8];
            bf16x8 a1 = *(const bf16x8*)&Ab[(wv*32 + 16 + l15)*LDA + lk8];
            bf16x8 w0 = *(const bf16x8*)&Wb[(     l15)*LDA + lk8];
            bf16x8 w1 = *(const bf16x8*)&Wb[(16 + l15)*LDA + lk8];
            acc00 = MFMA(a0, w0, acc00);
            acc01 = MFMA(a0, w1, acc01);
            acc10 = MFMA(a1, w0, acc10);
            acc11 = MFMA(a1, w1, acc11);
        }
        // write staged chunk c+1
        if (more) {
            __bf16* An = Abuf[(c + 1) & 1];
            #pragma unroll
            for (int p = 0; p < 4; ++p) {
                bf16x4 v = {(__bf16)fa[p].x, (__bf16)fa[p].y, (__bf16)fa[p].z, (__bf16)fa[p].w};
                *(bf16x4*)&An[(sb + 32*p)*LDA + kq4] = v;
            }
            __bf16* Wn = W1T[(c + 1) & 1];
            Wn[(h0w+0)*LDA + klw] = (__bf16)fw.x;
            Wn[(h0w+1)*LDA + klw] = (__bf16)fw.y;
            Wn[(h0w+2)*LDA + klw] = (__bf16)fw.z;
            Wn[(h0w+3)*LDA + klw] = (__bf16)fw.w;
        }
        __syncthreads();
    }

    // ---- layer-1 epilogue: bias+relu -> h1 (bf16, wave-local rows) ----
    const int mrow = wv * 32;
    #pragma unroll
    for (int r = 0; r < 4; ++r) {
        float v;
        v = acc00[r] + b1v0; h1s[(mrow +      r0 + r)*LDA +      l15] = (__bf16)(v > 0.f ? v : 0.f);
        v = acc01[r] + b1v1; h1s[(mrow +      r0 + r)*LDA + 16 + l15] = (__bf16)(v > 0.f ? v : 0.f);
        v = acc10[r] + b1v0; h1s[(mrow + 16 + r0 + r)*LDA +      l15] = (__bf16)(v > 0.f ? v : 0.f);
        v = acc11[r] + b1v1; h1s[(mrow + 16 + r0 + r)*LDA + 16 + l15] = (__bf16)(v > 0.f ? v : 0.f);
    }
    // (no barrier: each wave reads only its own 32 rows below)

    // ---- layer 2 ----
    const f32x4 z = {0.f, 0.f, 0.f, 0.f};
    f32x4 c200, c201, c210, c211;
    {
        bf16x8 a0 = *(const bf16x8*)&h1s[(mrow +      l15)*LDA + lk8];
        bf16x8 a1 = *(const bf16x8*)&h1s[(mrow + 16 + l15)*LDA + lk8];
        bf16x8 w0 = *(const bf16x8*)&W2T[(     l15)*LDA + lk8];
        bf16x8 w1 = *(const bf16x8*)&W2T[(16 + l15)*LDA + lk8];
        c200 = MFMA(a0, w0, z);
        c201 = MFMA(a0, w1, z);
        c210 = MFMA(a1, w0, z);
        c211 = MFMA(a1, w1, z);
    }
    __bf16* h2s = &Abuf[0][0];   // A-buffers dead after K-loop; reuse (wave-local rows)
    #pragma unroll
    for (int r = 0; r < 4; ++r) {
        float v;
        v = c200[r] + b2v0; h2s[(mrow +      r0 + r)*LDA +      l15] = (__bf16)(v > 0.f ? v : 0.f);
        v = c201[r] + b2v1; h2s[(mrow +      r0 + r)*LDA + 16 + l15] = (__bf16)(v > 0.f ? v : 0.f);
        v = c210[r] + b2v0; h2s[(mrow + 16 + r0 + r)*LDA +      l15] = (__bf16)(v > 0.f ? v : 0.f);
        v = c211[r] + b2v1; h2s[(mrow + 16 + r0 + r)*LDA + 16 + l15] = (__bf16)(v > 0.f ? v : 0.f);
    }

    // ---- layer 3 ----
    f32x4 c300, c301, c310, c311;
    {
        bf16x8 a0 = *(const bf16x8*)&h2s[(mrow +      l15)*LDA + lk8];
        bf16x8 a1 = *(const bf16x8*)&h2s[(mrow + 16 + l15)*LDA + lk8];
        bf16x8 w0 = *(const bf16x8*)&W3T[(     l15)*LDA + lk8];
        bf16x8 w1 = *(const bf16x8*)&W3T[(16 + l15)*LDA + lk8];
        c300 = MFMA(a0, w0, z);
        c301 = MFMA(a0, w1, z);
        c310 = MFMA(a1, w0, z);
        c311 = MFMA(a1, w1, z);
    }

    // ---- output: bias + relu + fp32 store ----
    const size_t orow = (size_t)(fi * BSZ + b0 + mrow);
    #pragma unroll
    for (int r = 0; r < 4; ++r) {
        float v;
        v = c300[r] + b3v0; out[(orow +      r0 + r)*HDIM +      l15] = v > 0.f ? v : 0.f;
        v = c301[r] + b3v1; out[(orow +      r0 + r)*HDIM + 16 + l15] = v > 0.f ? v : 0.f;
        v = c310[r] + b3v0; out[(orow + 16 + r0 + r)*HDIM +      l15] = v > 0.f ? v : 0.f;
        v = c311[r] + b3v1; out[(orow + 16 + r0 + r)*HDIM + 16 + l15] = v > 0.f ? v : 0.f;
    }
}

} // namespace

extern "C" void kernel_launch(void* const* d_in, const int* in_sizes, int n_in,
                              void* d_out, int out_size, void* d_ws, size_t ws_size,
                              hipStream_t stream) {
    const float* x  = (const float*)d_in[0];
    const float* W1 = (const float*)d_in[1];
    const float* b1 = (const float*)d_in[2];
    const float* W2 = (const float*)d_in[3];
    const float* b2 = (const float*)d_in[4];
    const float* W3 = (const float*)d_in[5];
    const float* b3 = (const float*)d_in[6];
    float* out = (float*)d_out;

    const dim3 grid(F_FEAT * (BSZ / BBLK));   // 310 * 16 = 4960
    const dim3 block(256);
    hipLaunchKernelGGL(sfp_mfma, grid, block, 0, stream,
                       x, W1, b1, W2, b2, W3, b3, out);
}

// Round 4
// 77.908 us; speedup vs baseline: 3.6409x; 1.3966x over previous
//
#include <hip/hip_runtime.h>

namespace {

constexpr int F_FEAT = 310;
constexpr int KDIM   = 309;
constexpr int BSZ    = 2048;
constexpr int HDIM   = 32;
constexpr int NCH    = 10;          // K chunks of 32 (309 -> 320, zero-padded in W1T)
constexpr int NX     = F_FEAT * BSZ;          // 634880 x elements

// workspace layout
constexpr int    NBLK8   = NX / 8 + 2;        // 79362 16B blocks per x copy
constexpr size_t CSTR_B  = (size_t)NBLK8 * 16;        // bytes per x copy (16B aligned)
constexpr size_t XC_BYTES = CSTR_B * 8;               // 8 shift copies
constexpr size_t W1T_FSTR = 32 * 640;                 // 32 h rows * 320 k * 2B
constexpr size_t W1T_OFF  = XC_BYTES;
constexpr size_t W2T_OFF  = W1T_OFF + (size_t)F_FEAT * W1T_FSTR;
constexpr size_t WT_FSTR  = 2048;                     // 32*32*2B
constexpr size_t W3T_OFF  = W2T_OFF + (size_t)F_FEAT * WT_FSTR;
constexpr size_t WS_NEED  = W3T_OFF + (size_t)F_FEAT * WT_FSTR;   // ~17.8 MB

typedef __bf16 bf16x8 __attribute__((ext_vector_type(8)));
typedef __bf16 bf16x4 __attribute__((ext_vector_type(4)));
typedef float  f32x4  __attribute__((ext_vector_type(4)));

#define MFMA(a, b, c) __builtin_amdgcn_mfma_f32_16x16x32_bf16((a), (b), (c), 0, 0, 0)

// ---------- convert x -> 8 shift-aligned bf16 copies ----------
// copy c holds xflat[i] at element position i+c; positions outside [0,NX) are 0.
__global__ __launch_bounds__(256) void cvt_x(const float* __restrict__ x,
                                             char* __restrict__ ws) {
    const int m = blockIdx.x * 256 + threadIdx.x;
    const int c = blockIdx.y;
    if (m >= NBLK8) return;
    const int e0 = m * 8 - c;
    bf16x8 v;
    #pragma unroll
    for (int q = 0; q < 8; ++q) {
        const int i = e0 + q;
        const float f = (i >= 0 && i < NX) ? x[i] : 0.f;
        v[q] = (__bf16)f;
    }
    *(bf16x8*)(ws + (size_t)c * CSTR_B + (size_t)m * 16) = v;
}

// ---------- convert W1/W2/W3 -> transposed bf16 (W1T pre-swizzled, k-padded) ----------
__global__ __launch_bounds__(256) void cvt_w(const float* __restrict__ W1,
                                             const float* __restrict__ W2,
                                             const float* __restrict__ W3,
                                             char* __restrict__ ws) {
    __shared__ float tile[32][33];
    const int fi = blockIdx.x, tid = threadIdx.x;
    const int kl = tid >> 3;          // 0..31
    const int h4 = (tid & 7) * 4;     // 0,4,..,28

    // W1: [309][32] fp32 -> pre-swizzled bf16 [32 h][320 k] (k>=309 zero)
    {
        const float* Wg = W1 + (size_t)fi * KDIM * HDIM;
        char* wt = ws + W1T_OFF + (size_t)fi * W1T_FSTR;
        for (int kc = 0; kc < NCH; ++kc) {
            const int k = kc * 32 + kl;
            float4 f = (k < KDIM) ? *(const float4*)&Wg[k * HDIM + h4]
                                  : make_float4(0.f, 0.f, 0.f, 0.f);
            tile[kl][h4 + 0] = f.x; tile[kl][h4 + 1] = f.y;
            tile[kl][h4 + 2] = f.z; tile[kl][h4 + 3] = f.w;
            __syncthreads();
            const int h = kl, kq = h4;          // writer roles
            bf16x4 o;
            #pragma unroll
            for (int j = 0; j < 4; ++j) o[j] = (__bf16)tile[kq + j][h];
            const int boff = (h * 640 + 2 * (kc * 32 + kq)) ^ ((h & 7) << 4);
            *(bf16x4*)(wt + boff) = o;
            __syncthreads();
        }
    }
    // W2 / W3: [32][32] fp32 -> plain transposed bf16 [h][k]
    {
        const float* Wg = W2 + (size_t)fi * HDIM * HDIM;
        char* wt = ws + W2T_OFF + (size_t)fi * WT_FSTR;
        float4 f = *(const float4*)&Wg[kl * HDIM + h4];
        tile[kl][h4 + 0] = f.x; tile[kl][h4 + 1] = f.y;
        tile[kl][h4 + 2] = f.z; tile[kl][h4 + 3] = f.w;
        __syncthreads();
        bf16x4 o;
        #pragma unroll
        for (int j = 0; j < 4; ++j) o[j] = (__bf16)tile[h4 + j][kl];
        *(bf16x4*)(wt + (kl * 32 + h4) * 2) = o;
        __syncthreads();
    }
    {
        const float* Wg = W3 + (size_t)fi * HDIM * HDIM;
        char* wt = ws + W3T_OFF + (size_t)fi * WT_FSTR;
        float4 f = *(const float4*)&Wg[kl * HDIM + h4];
        tile[kl][h4 + 0] = f.x; tile[kl][h4 + 1] = f.y;
        tile[kl][h4 + 2] = f.z; tile[kl][h4 + 3] = f.w;
        __syncthreads();
        bf16x4 o;
        #pragma unroll
        for (int j = 0; j < 4; ++j) o[j] = (__bf16)tile[h4 + j][kl];
        *(bf16x4*)(wt + (kl * 32 + h4) * 2) = o;
    }
}

// ---------- fused per-feature MLP ----------
template<bool FAST>
__global__ __launch_bounds__(256) void sfp2(
    const float* __restrict__ x,
    const float* __restrict__ W1, const float* __restrict__ b1,
    const float* __restrict__ W2, const float* __restrict__ b2,
    const float* __restrict__ W3, const float* __restrict__ b3,
    const char* __restrict__ ws, float* __restrict__ out)
{
    __shared__ __attribute__((aligned(16))) __bf16 W1s[32 * 320];   // 20480 B, swizzled
    __shared__ __attribute__((aligned(16))) __bf16 h1s[128 * 40];   // 10240 B

    int fi, sb;
    if (FAST) {
        // XCD-clustered decode: all 16 sample blocks of a feature on one XCD.
        const int xc = blockIdx.x & 7, li = blockIdx.x >> 3;
        const int cnt = (xc < 6) ? 39 : 38;          // 310 = 6*39 + 2*38
        const int lf = li >> 4;
        if (lf >= cnt) return;
        fi = ((xc < 6) ? xc * 39 : 234 + (xc - 6) * 38) + lf;
        sb = li & 15;
    } else {
        fi = blockIdx.x >> 4; sb = blockIdx.x & 15;
    }

    const int tid = threadIdx.x, lane = tid & 63, wv = tid >> 6;
    const int l15 = lane & 15, l16 = lane >> 4;
    const int lk8 = l16 * 8, r0 = l16 * 4;
    const int b0 = sb << 7, iB = fi << 11;

    if (FAST) {   // stage pre-swizzled W1T once (linear copy)
        const char* src = ws + W1T_OFF + (size_t)fi * W1T_FSTR;
        #pragma unroll
        for (int i = 0; i < 5; ++i) {
            const int off = i * 4096 + tid * 16;
            *(bf16x8*)((char*)W1s + off) = *(const bf16x8*)(src + off);
        }
        __syncthreads();
    }

    const float b1v0 = b1[fi*HDIM + l15], b1v1 = b1[fi*HDIM + 16 + l15];
    const float b2v0 = b2[fi*HDIM + l15], b2v1 = b2[fi*HDIM + 16 + l15];
    const float b3v0 = b3[fi*HDIM + l15], b3v1 = b3[fi*HDIM + 16 + l15];

    auto loadA = [&](int lin) -> bf16x8 {
        if (FAST) {
            if ((unsigned)(iB - 1 - lin) < 7u) {        // fragment straddles LOO cut
                bf16x8 r;
                #pragma unroll
                for (int q = 0; q < 8; ++q) {
                    int i = lin + q; i += (i >= iB) ? BSZ : 0;
                    r[q] = *(const __bf16*)(ws + (size_t)i * 2);   // copy 0
                }
                return r;
            }
            const int e  = lin + ((lin >= iB) ? BSZ : 0);
            const int c8 = (-e) & 7;
            return *(const bf16x8*)(ws + (size_t)c8 * CSTR_B + (size_t)(e + c8) * 2);
        } else {
            bf16x8 r;
            #pragma unroll
            for (int q = 0; q < 8; ++q) {
                int i = lin + q; i += (i >= iB) ? BSZ : 0;
                i = (i < NX) ? i : (NX - 1);            // k>=309 garbage, W=0 kills it
                r[q] = (__bf16)x[i];
            }
            return r;
        }
    };

    auto loadW1f = [&](int c, int hrow) -> bf16x8 {
        if (FAST) {
            const int boff = (hrow * 640 + 2 * (c * 32 + lk8)) ^ ((hrow & 7) << 4);
            return *(const bf16x8*)((const char*)W1s + boff);
        } else {
            const float* Wg = W1 + (size_t)fi * KDIM * HDIM;
            bf16x8 r;
            #pragma unroll
            for (int q = 0; q < 8; ++q) {
                const int k = c * 32 + lk8 + q;
                r[q] = (__bf16)((k < KDIM) ? Wg[k * HDIM + hrow] : 0.f);
            }
            return r;
        }
    };

    // ---------------- layer 1: zero-barrier pipelined K-loop ----------------
    f32x4 acc00 = {0,0,0,0}, acc01 = {0,0,0,0}, acc10 = {0,0,0,0}, acc11 = {0,0,0,0};
    const int mrow = wv * 32;
    const int lin0 = (b0 + mrow + l15) * KDIM + lk8;
    const int lin1 = lin0 + 16 * KDIM;

    bf16x8 a0 = loadA(lin0),        a1 = loadA(lin1);
    bf16x8 w0 = loadW1f(0, l15),    w1 = loadW1f(0, 16 + l15);
    for (int c = 0; c < NCH; ++c) {
        bf16x8 na0, na1, nw0, nw1;
        if (c + 1 < NCH) {
            na0 = loadA(lin0 + 32 * (c + 1));
            na1 = loadA(lin1 + 32 * (c + 1));
            nw0 = loadW1f(c + 1, l15);
            nw1 = loadW1f(c + 1, 16 + l15);
        }
        acc00 = MFMA(a0, w0, acc00);
        acc01 = MFMA(a0, w1, acc01);
        acc10 = MFMA(a1, w0, acc10);
        acc11 = MFMA(a1, w1, acc11);
        a0 = na0; a1 = na1; w0 = nw0; w1 = nw1;
    }

    // ---- bias+relu -> h1 (wave-local LDS transpose, no barrier) ----
    constexpr int LDA = 40;
    #pragma unroll
    for (int r = 0; r < 4; ++r) {
        float v;
        v = acc00[r] + b1v0; h1s[(mrow +      r0 + r)*LDA +      l15] = (__bf16)(v > 0.f ? v : 0.f);
        v = acc01[r] + b1v1; h1s[(mrow +      r0 + r)*LDA + 16 + l15] = (__bf16)(v > 0.f ? v : 0.f);
        v = acc10[r] + b1v0; h1s[(mrow + 16 + r0 + r)*LDA +      l15] = (__bf16)(v > 0.f ? v : 0.f);
        v = acc11[r] + b1v1; h1s[(mrow + 16 + r0 + r)*LDA + 16 + l15] = (__bf16)(v > 0.f ? v : 0.f);
    }

    auto loadW23 = [&](const float* Wg, size_t toff, int hrow) -> bf16x8 {
        if (FAST) {
            return *(const bf16x8*)(ws + toff + (size_t)fi * WT_FSTR
                                    + (size_t)(hrow * 32 + lk8) * 2);
        } else {
            bf16x8 r;
            #pragma unroll
            for (int q = 0; q < 8; ++q)
                r[q] = (__bf16)Wg[(size_t)fi * HDIM * HDIM + (lk8 + q) * HDIM + hrow];
            return r;
        }
    };

    // ---------------- layer 2 ----------------
    const f32x4 z = {0,0,0,0};
    f32x4 c200, c201, c210, c211;
    {
        bf16x8 ha0 = *(const bf16x8*)&h1s[(mrow +      l15)*LDA + lk8];
        bf16x8 ha1 = *(const bf16x8*)&h1s[(mrow + 16 + l15)*LDA + lk8];
        bf16x8 v0 = loadW23(W2, W2T_OFF, l15);
        bf16x8 v1 = loadW23(W2, W2T_OFF, 16 + l15);
        c200 = MFMA(ha0, v0, z); c201 = MFMA(ha0, v1, z);
        c210 = MFMA(ha1, v0, z); c211 = MFMA(ha1, v1, z);
    }
    #pragma unroll
    for (int r = 0; r < 4; ++r) {
        float v;
        v = c200[r] + b2v0; h1s[(mrow +      r0 + r)*LDA +      l15] = (__bf16)(v > 0.f ? v : 0.f);
        v = c201[r] + b2v1; h1s[(mrow +      r0 + r)*LDA + 16 + l15] = (__bf16)(v > 0.f ? v : 0.f);
        v = c210[r] + b2v0; h1s[(mrow + 16 + r0 + r)*LDA +      l15] = (__bf16)(v > 0.f ? v : 0.f);
        v = c211[r] + b2v1; h1s[(mrow + 16 + r0 + r)*LDA + 16 + l15] = (__bf16)(v > 0.f ? v : 0.f);
    }

    // ---------------- layer 3 ----------------
    f32x4 c300, c301, c310, c311;
    {
        bf16x8 ha0 = *(const bf16x8*)&h1s[(mrow +      l15)*LDA + lk8];
        bf16x8 ha1 = *(const bf16x8*)&h1s[(mrow + 16 + l15)*LDA + lk8];
        bf16x8 v0 = loadW23(W3, W3T_OFF, l15);
        bf16x8 v1 = loadW23(W3, W3T_OFF, 16 + l15);
        c300 = MFMA(ha0, v0, z); c301 = MFMA(ha0, v1, z);
        c310 = MFMA(ha1, v0, z); c311 = MFMA(ha1, v1, z);
    }

    // ---------------- output ----------------
    const size_t orow = (size_t)(fi * BSZ + b0 + mrow);
    #pragma unroll
    for (int r = 0; r < 4; ++r) {
        float v;
        v = c300[r] + b3v0; out[(orow +      r0 + r)*HDIM +      l15] = v > 0.f ? v : 0.f;
        v = c301[r] + b3v1; out[(orow +      r0 + r)*HDIM + 16 + l15] = v > 0.f ? v : 0.f;
        v = c310[r] + b3v0; out[(orow + 16 + r0 + r)*HDIM +      l15] = v > 0.f ? v : 0.f;
        v = c311[r] + b3v1; out[(orow + 16 + r0 + r)*HDIM + 16 + l15] = v > 0.f ? v : 0.f;
    }
}

} // namespace

extern "C" void kernel_launch(void* const* d_in, const int* in_sizes, int n_in,
                              void* d_out, int out_size, void* d_ws, size_t ws_size,
                              hipStream_t stream) {
    const float* x  = (const float*)d_in[0];
    const float* W1 = (const float*)d_in[1];
    const float* b1 = (const float*)d_in[2];
    const float* W2 = (const float*)d_in[3];
    const float* b2 = (const float*)d_in[4];
    const float* W3 = (const float*)d_in[5];
    const float* b3 = (const float*)d_in[6];
    float* out = (float*)d_out;
    char* ws = (char*)d_ws;

    const bool fast = (ws != nullptr) && (ws_size >= WS_NEED);
    if (fast) {
        hipLaunchKernelGGL(cvt_x, dim3((NBLK8 + 255) / 256, 8), dim3(256), 0, stream, x, ws);
        hipLaunchKernelGGL(cvt_w, dim3(F_FEAT), dim3(256), 0, stream, W1, W2, W3, ws);
        hipLaunchKernelGGL((sfp2<true>), dim3(8 * 39 * 16), dim3(256), 0, stream,
                           x, W1, b1, W2, b2, W3, b3, ws, out);
    } else {
        hipLaunchKernelGGL((sfp2<false>), dim3(F_FEAT * 16), dim3(256), 0, stream,
                           x, W1, b1, W2, b2, W3, b3, ws, out);
    }
}